// Round 7
// baseline (166.407 us; speedup 1.0000x reference)
//
#include <hip/hip_runtime.h>

#define GS 64
#define BB 128
#define NN 8192
#define KK 3
#define SLICE_FLOATS (GS * GS * GS * 3)   // 786432 floats = 3 MB per b
#define B_PER_XCD 16
#define BLOCKS_PER_B 16                   // 16 blocks x 512 pts (2 pts/thread)
#define GRID (BB * BLOCKS_PER_B)          // 2048
#define NSTREAM 12                        // 2 pts x 3 k x {reflect,rotate}

// One thread = two (b, point) items, all 3 k's, reflect+rotate
// => 12 independent gathers in flight. Per-XCD block ordering walks b's
// sequentially (xcd = blockIdx & 7 round-robin) so each 3 MB cp slice is
// gathered while L2-resident. No contended atomics for the loss; final
// reduction fused via last-block-done (release fence -> device atomicAdd ->
// acquire fence -> reduce partials).
__global__ __launch_bounds__(256) void symloss_main(
    const float* __restrict__ points, const float* __restrict__ cp,
    const float* __restrict__ plane, const float* __restrict__ quat,
    float2* __restrict__ partials, unsigned* __restrict__ ctr,
    float* __restrict__ out) {
    int raw = blockIdx.x;
    int xcd = raw & 7;
    int s   = raw >> 3;                   // 0..255 per XCD
    int b   = xcd * B_PER_XCD + s / BLOCKS_PER_B;
    int chunk = s % BLOCKS_PER_B;         // 0..15
    int n0 = chunk * 512 + threadIdx.x;   // second point at +256

    const float* cpb = cp + (size_t)b * SLICE_FLOATS;

    float px[2], py[2], pz[2];
#pragma unroll
    for (int t = 0; t < 2; ++t) {
        const float* p = points + ((size_t)b * NN + n0 + t * 256) * 3;
        px[t] = p[0]; py[t] = p[1]; pz[t] = p[2];
    }

    // transformed coords: slots [0..5] = reflect (k*2+t), [6..11] = rotate
    float tx[NSTREAM], ty[NSTREAM], tz[NSTREAM];

#pragma unroll
    for (int k = 0; k < KK; ++k) {
        const float* plk = plane + ((size_t)k * BB + b) * 4;
        float nx = plk[0], ny = plk[1], nz = plk[2], d = plk[3];
        float denom = nx * nx + ny * ny + nz * nz + 1e-12f;

        const float* q = quat + ((size_t)k * BB + b) * 4;
        float qw = q[0], qx = q[1], qy = q[2], qz = q[3];
        float qn = sqrtf(qw * qw + qx * qx + qy * qy + qz * qz) + 1e-12f;
        qw /= qn; qx /= qn; qy /= qn; qz /= qn;

#pragma unroll
        for (int t = 0; t < 2; ++t) {
            int i = k * 2 + t;
            float tt = (px[t] * nx + py[t] * ny + pz[t] * nz + d) / denom;
            tx[i] = px[t] - 2.0f * tt * nx;
            ty[i] = py[t] - 2.0f * tt * ny;
            tz[i] = pz[t] - 2.0f * tt * nz;

            float ux = qy * pz[t] - qz * py[t];
            float uy = qz * px[t] - qx * pz[t];
            float uz = qx * py[t] - qy * px[t];
            float sx = ux + qw * px[t];
            float sy = uy + qw * py[t];
            float sz = uz + qw * pz[t];
            tx[6 + i] = px[t] + 2.0f * (qy * sz - qz * sy);
            ty[6 + i] = py[t] + 2.0f * (qz * sx - qx * sz);
            tz[6 + i] = pz[t] + 2.0f * (qx * sy - qy * sx);
        }
    }

    // all 12 cell addresses, then all 12 gathers back-to-back
    const float* cptr[NSTREAM];
#pragma unroll
    for (int i = 0; i < NSTREAM; ++i) {
        float fx = fminf(fmaxf(floorf((tx[i] + 0.5f) * 64.0f), 0.0f), 63.0f);
        float fy = fminf(fmaxf(floorf((ty[i] + 0.5f) * 64.0f), 0.0f), 63.0f);
        float fz = fminf(fmaxf(floorf((tz[i] + 0.5f) * 64.0f), 0.0f), 63.0f);
        int flat = (((int)fx * GS) + (int)fy) * GS + (int)fz;
        cptr[i] = cpb + (size_t)flat * 3;
    }
    float cx[NSTREAM], cy[NSTREAM], cz[NSTREAM];
#pragma unroll
    for (int i = 0; i < NSTREAM; ++i) {
        cx[i] = cptr[i][0];
        cy[i] = cptr[i][1];
        cz[i] = cptr[i][2];
    }

    float ref_acc = 0.0f, rot_acc = 0.0f;
#pragma unroll
    for (int i = 0; i < 6; ++i) {
        float dx = tx[i] - cx[i], dy = ty[i] - cy[i], dz = tz[i] - cz[i];
        ref_acc += dx * dx + dy * dy + dz * dz;
    }
#pragma unroll
    for (int i = 6; i < NSTREAM; ++i) {
        float dx = tx[i] - cx[i], dy = ty[i] - cy[i], dz = tz[i] - cz[i];
        rot_acc += dx * dx + dy * dy + dz * dz;
    }

    // ---- block reduction: shuffle (width 64) -> LDS ----
    for (int off = 32; off > 0; off >>= 1) {
        ref_acc += __shfl_down(ref_acc, off, 64);
        rot_acc += __shfl_down(rot_acc, off, 64);
    }
    __shared__ float s_ref[4], s_rot[4];
    int wave = threadIdx.x >> 6;
    int lane = threadIdx.x & 63;
    if (lane == 0) {
        s_ref[wave] = ref_acc;
        s_rot[wave] = rot_acc;
    }
    __syncthreads();

    // ---- store partial, last-block-done fused finalize ----
    __shared__ int is_last;
    if (threadIdx.x == 0) {
        float2 v;
        v.x = s_ref[0] + s_ref[1] + s_ref[2] + s_ref[3];
        v.y = s_rot[0] + s_rot[1] + s_rot[2] + s_rot[3];
        partials[blockIdx.x] = v;
        __threadfence();                       // release partial
        unsigned old = atomicAdd(ctr, 1u);     // device scope
        is_last = (old == (unsigned)(GRID - 1));
    }
    __syncthreads();

    if (is_last) {
        __threadfence();                       // acquire others' partials
        double r = 0.0, o = 0.0;
        for (int i = threadIdx.x; i < GRID; i += 256) {
            float2 v = partials[i];
            r += (double)v.x;
            o += (double)v.y;
        }
        __shared__ double d_r[256], d_o[256];
        d_r[threadIdx.x] = r;
        d_o[threadIdx.x] = o;
        __syncthreads();
        for (int off = 128; off > 0; off >>= 1) {
            if (threadIdx.x < off) {
                d_r[threadIdx.x] += d_r[threadIdx.x + off];
                d_o[threadIdx.x] += d_o[threadIdx.x + off];
            }
            __syncthreads();
        }
        if (threadIdx.x == 0) {
            const double inv = 1.0 / ((double)BB * (double)NN);
            out[0] = (float)(d_r[0] * inv);
            out[1] = (float)(d_o[0] * inv);
        }
    }
}

extern "C" void kernel_launch(void* const* d_in, const int* in_sizes, int n_in,
                              void* d_out, int out_size, void* d_ws, size_t ws_size,
                              hipStream_t stream) {
    const float* points = (const float*)d_in[0];
    const float* cp     = (const float*)d_in[1];
    // d_in[2] = voxel (unused)
    const float* plane  = (const float*)d_in[3];
    const float* quat   = (const float*)d_in[4];
    float* out = (float*)d_out;

    float2*   partials = (float2*)d_ws;                      // 2048*8 = 16 KB
    unsigned* ctr      = (unsigned*)((char*)d_ws + 16384);   // 4 B

    hipMemsetAsync(ctr, 0, 4, stream);   // zero the completion counter
    symloss_main<<<GRID, 256, 0, stream>>>(points, cp, plane, quat,
                                           partials, ctr, out);
}

// Round 8
// 64.602 us; speedup vs baseline: 2.5759x; 2.5759x over previous
//
#include <hip/hip_runtime.h>

#define GS 64
#define BB 128
#define NN 8192
#define KK 3
#define SLICE_FLOATS (GS * GS * GS * 3)   // 786432 floats = 3 MB per b
#define B_PER_XCD 16
#define BLOCKS_PER_B 32                   // 32 chunks of 256 pts; all k per thread
#define GRID (BB * BLOCKS_PER_B)          // 4096

// One thread = one (b, point): all 3 k's, reflect+rotate => 6 independent
// gathers in flight. Per-XCD block ordering walks b's sequentially
// (xcd = blockIdx & 7 round-robin) keeping the live b-window small =>
// L2/L3-resident gathers. No contended atomics. __launch_bounds__(256,8)
// pins 8 waves/SIMD (VGPR <= 64) — round 7 showed fat threads kill this.
__global__ __launch_bounds__(256, 8) void symloss_main(
    const float* __restrict__ points, const float* __restrict__ cp,
    const float* __restrict__ plane, const float* __restrict__ quat,
    float2* __restrict__ partials) {
    int raw = blockIdx.x;
    int xcd = raw & 7;
    int s   = raw >> 3;                   // 0..511 per XCD
    int b   = xcd * B_PER_XCD + s / BLOCKS_PER_B;
    int chunk = s % BLOCKS_PER_B;         // 0..31
    int n = chunk * 256 + threadIdx.x;

    const float* p = points + ((size_t)b * NN + n) * 3;
    float px = p[0], py = p[1], pz = p[2];
    const float* cpb = cp + (size_t)b * SLICE_FLOATS;

    // transformed coords for all 6 streams: [0..2] reflect, [3..5] rotate
    float tx[2 * KK], ty[2 * KK], tz[2 * KK];

#pragma unroll
    for (int k = 0; k < KK; ++k) {
        // ---- reflect (b,k uniform per block -> scalar loads) ----
        const float* plk = plane + ((size_t)k * BB + b) * 4;
        float nx = plk[0], ny = plk[1], nz = plk[2], d = plk[3];
        float denom = nx * nx + ny * ny + nz * nz + 1e-12f;
        float tt = (px * nx + py * ny + pz * nz + d) / denom;
        tx[k] = px - 2.0f * tt * nx;
        ty[k] = py - 2.0f * tt * ny;
        tz[k] = pz - 2.0f * tt * nz;

        // ---- rotate ----
        const float* q = quat + ((size_t)k * BB + b) * 4;
        float qw = q[0], qx = q[1], qy = q[2], qz = q[3];
        float qn = sqrtf(qw * qw + qx * qx + qy * qy + qz * qz) + 1e-12f;
        qw /= qn; qx /= qn; qy /= qn; qz /= qn;
        float ux = qy * pz - qz * py;
        float uy = qz * px - qx * pz;
        float uz = qx * py - qy * px;
        float sx = ux + qw * px;
        float sy = uy + qw * py;
        float sz = uz + qw * pz;
        tx[KK + k] = px + 2.0f * (qy * sz - qz * sy);
        ty[KK + k] = py + 2.0f * (qz * sx - qx * sz);
        tz[KK + k] = pz + 2.0f * (qx * sy - qy * sx);
    }

    // ---- compute all 6 flat indices (ints, not pointers: saves VGPRs) ----
    int flat[2 * KK];
#pragma unroll
    for (int i = 0; i < 2 * KK; ++i) {
        float fx = fminf(fmaxf(floorf((tx[i] + 0.5f) * 64.0f), 0.0f), 63.0f);
        float fy = fminf(fmaxf(floorf((ty[i] + 0.5f) * 64.0f), 0.0f), 63.0f);
        float fz = fminf(fmaxf(floorf((tz[i] + 0.5f) * 64.0f), 0.0f), 63.0f);
        flat[i] = (((int)fx * GS) + (int)fy) * GS + (int)fz;
    }

    // ---- issue all 6 gathers, then consume ----
    float cx[2 * KK], cy[2 * KK], cz[2 * KK];
#pragma unroll
    for (int i = 0; i < 2 * KK; ++i) {
        const float* c = cpb + (size_t)flat[i] * 3;
        cx[i] = c[0];
        cy[i] = c[1];
        cz[i] = c[2];
    }

    float ref_acc = 0.0f, rot_acc = 0.0f;
#pragma unroll
    for (int i = 0; i < KK; ++i) {
        float dx = tx[i] - cx[i], dy = ty[i] - cy[i], dz = tz[i] - cz[i];
        ref_acc += dx * dx + dy * dy + dz * dz;
    }
#pragma unroll
    for (int i = KK; i < 2 * KK; ++i) {
        float dx = tx[i] - cx[i], dy = ty[i] - cy[i], dz = tz[i] - cz[i];
        rot_acc += dx * dx + dy * dy + dz * dz;
    }

    // ---- block reduction: shuffle (width 64) -> LDS -> one plain store ----
    for (int off = 32; off > 0; off >>= 1) {
        ref_acc += __shfl_down(ref_acc, off, 64);
        rot_acc += __shfl_down(rot_acc, off, 64);
    }
    __shared__ float s_ref[4], s_rot[4];
    int wave = threadIdx.x >> 6;
    int lane = threadIdx.x & 63;
    if (lane == 0) {
        s_ref[wave] = ref_acc;
        s_rot[wave] = rot_acc;
    }
    __syncthreads();
    if (threadIdx.x == 0) {
        float2 v;
        v.x = s_ref[0] + s_ref[1] + s_ref[2] + s_ref[3];
        v.y = s_rot[0] + s_rot[1] + s_rot[2] + s_rot[3];
        partials[blockIdx.x] = v;   // distinct slot per block, no atomics
    }
}

__global__ __launch_bounds__(1024) void finalize_kernel(
    const float2* __restrict__ partials, float* __restrict__ out) {
    double r = 0.0, o = 0.0;
    for (int i = threadIdx.x; i < GRID; i += 1024) {
        float2 v = partials[i];
        r += (double)v.x;
        o += (double)v.y;
    }
    __shared__ double s_r[1024], s_o[1024];
    s_r[threadIdx.x] = r;
    s_o[threadIdx.x] = o;
    __syncthreads();
    for (int off = 512; off > 0; off >>= 1) {
        if (threadIdx.x < off) {
            s_r[threadIdx.x] += s_r[threadIdx.x + off];
            s_o[threadIdx.x] += s_o[threadIdx.x + off];
        }
        __syncthreads();
    }
    if (threadIdx.x == 0) {
        const double inv = 1.0 / ((double)BB * (double)NN);
        out[0] = (float)(s_r[0] * inv);
        out[1] = (float)(s_o[0] * inv);
    }
}

extern "C" void kernel_launch(void* const* d_in, const int* in_sizes, int n_in,
                              void* d_out, int out_size, void* d_ws, size_t ws_size,
                              hipStream_t stream) {
    const float* points = (const float*)d_in[0];
    const float* cp     = (const float*)d_in[1];
    // d_in[2] = voxel (unused)
    const float* plane  = (const float*)d_in[3];
    const float* quat   = (const float*)d_in[4];
    float* out = (float*)d_out;
    float2* partials = (float2*)d_ws;     // 4096 * 8 B = 32 KB

    symloss_main<<<GRID, 256, 0, stream>>>(points, cp, plane, quat, partials);
    finalize_kernel<<<1, 1024, 0, stream>>>(partials, out);
}